// Round 9
// baseline (282.656 us; speedup 1.0000x reference)
//
#include <hip/hip_runtime.h>
#include <math.h>

// Fully-fused SINGLE-KERNEL pipeline (R9): tests the launch-boundary cost.
// R7's 3-kernel structure is collapsed into one dispatch:
//  - k0_prep deleted: each block builds w2bL [64][104] bf16 (bank-pad) and
//    w1bL [2][16][32] hi/lo in LDS during a short prologue; conv3 reads w3
//    as RAW F32 + inline f2bf (bit-identical conversion, w3 is L2-resident).
//  - k_soft deleted: partials published with device-scope release atomics;
//    an atomic counter elects the last block, which acquire-loads all 512
//    partial rows and performs the softmax (cross-XCD-safe, G16).
//  - R8's reg-prefetch reverted (measured neutral): R7 staging restored.
// Main loop is R7 bit-identical: conv1 on MFMA via hi/lo bf16 split
// (exact fp32 dot: (w_hi+w_lo)x_hi + (w_hi+w_lo)x_lo), conv2/conv3 MFMA,
// pool/bias/relu per-lane, wave-private LDS arenas, zero in-loop barriers.
//   per q: stage 16x128 floats -> hi/lo planes -> conv1 = 60 MFMA + pool1
//   -> h1t -> conv2 = 12 MFMA vs w2bL -> bias+relu+pool2 -> pk regs ->
//   (after loop) sh2 tile -> conv3 GEMM (K=256, w3 inline-cvt) -> relu ->
//   logits partials vs wl -> butterfly -> partials[512][3] -> last block:
//   sum + bl -> softmax -> out[256][3].

typedef __attribute__((ext_vector_type(8))) short bf16x8;
typedef __attribute__((ext_vector_type(4))) float f32x4;

__device__ __forceinline__ ushort f2bf(float f) {
    union { float f; uint u; } c; c.f = f;
    return (ushort)((c.u + 0x7FFFu + ((c.u >> 16) & 1u)) >> 16);   // RNE
}

#define S2  264   // sh2 row stride (ushorts): 528B rows, 16B-aligned
#define XPS 136   // x hi/lo plane row stride (ushorts): 272B, 16B-aligned
#define H1S 104   // h1t row stride (ushorts): 208B; 52 dw -> 2-way-free banks
#define W2S 104   // w2bL row stride (ushorts): 208B; 2-way-free (96 would be 8-way)

__global__ __launch_bounds__(256) void k_fused(
    const float* __restrict__ x,     // [32768][1216]
    const float* __restrict__ w1,    // [32][10]
    const float* __restrict__ b1,    // [32]
    const float* __restrict__ w2,    // [64][32][3]
    const float* __restrict__ b2,    // [64]
    const float* __restrict__ w3,    // [128][256] flat f32
    const float* __restrict__ b3,    // [128]
    const float* __restrict__ wl,    // [3][16384]
    const float* __restrict__ blg,   // [3]
    float* __restrict__ partials,    // [512][3]
    uint*  __restrict__ cnt,         // zeroed per launch
    float* __restrict__ out)         // [256][3]
{
    // per-wave arena: hi plane | lo plane | h1t  (sh2 overlays after q loop)
    __shared__ __align__(16) ushort arena[4][6016];   // 48,128 B
    __shared__ __align__(16) ushort w2bL[64 * W2S];   // 13,312 B
    __shared__ __align__(16) ushort w1bL[1024];       //  2,048 B
    __shared__ float red[4][3];
    __shared__ int sh_last;
    const int tid  = threadIdx.x;
    const int wave = tid >> 6, lane = tid & 63;
    const int lm   = lane & 15, quad = lane >> 4, qm = quad & 1;
    const int bn0  = blockIdx.x * 64 + wave * 16;
    const float* xw0 = x + (size_t)bn0 * 1216;     // wave's 16 series rows

    // ---- prologue: build w2bL / w1bL in LDS (bit-identical to old k0) ----
    for (int i = tid; i < 6144; i += 256) {        // w2[c][ci][d] -> [c][d*32+ci]
        int c = i / 96, r = i - c * 96;
        int ci = r / 3, d = r - ci * 3;
        w2bL[c * W2S + d * 32 + ci] = f2bf(w2[i]);
    }
    for (int i = tid; i < 1024; i += 256) {        // w1: hi@3..12, lo@19..28
        int H = i >> 9, r9 = i & 511, c = r9 >> 5, k = r9 & 31;
        int ch = H * 16 + c;
        ushort val = 0;
        if (k >= 3 && k <= 12) {
            val = (ushort)(__float_as_uint(w1[ch * 10 + k - 3]) >> 16);  // hi=trunc
        } else if (k >= 19 && k <= 28) {
            float w = w1[ch * 10 + k - 19];
            float hf = __uint_as_float(__float_as_uint(w) & 0xFFFF0000u);
            val = f2bf(w - hf);                                          // lo=RNE
        }
        w1bL[i] = val;
    }
    __syncthreads();

    ushort* hp  = arena[wave];            // x_hi plane
    ushort* lp  = hp + 16 * XPS;          // x_lo plane
    ushort* h1t = lp + 16 * XPS;          // per-q pooled conv1 tile [16][3][32]

    // hoisted fragments / biases
    const bf16x8 wA0 = *(const bf16x8*)(w1bL + lm * 32 + quad * 8);        // ch 0-15
    const bf16x8 wA1 = *(const bf16x8*)(w1bL + 512 + lm * 32 + quad * 8);  // ch 16-31
    const f32x4  b1i0 = *(const f32x4*)(b1 + quad * 4);       // rows quad*4+r
    const f32x4  b1i1 = *(const f32x4*)(b1 + 16 + quad * 4);
    float bias2[4];
    #pragma unroll
    for (int nt = 0; nt < 4; ++nt) bias2[nt] = b2[nt * 16 + lm];

    f32x4 cur[4];
    #pragma unroll
    for (int nt = 0; nt < 4; ++nt) cur[nt] = (f32x4){-3e38f,-3e38f,-3e38f,-3e38f};
    uint2 pk[4][4];                       // packed pooled conv2 bf16 [nt][r]

    for (int q = 0; q < 10; ++q) {
        // ---- stage x[16 rows][fq .. fq+123] -> hi/lo bf16 planes ----
        // (wave-private: no barriers; 32 consecutive lanes cover one row)
        const int fq = 120 * q - 4;
        #pragma unroll
        for (int j = 0; j < 8; ++j) {
            const int idx = lane + 64 * j;          // 0..511
            const int row = idx >> 5, c4 = idx & 31;
            const int off = fq + 4 * c4;
            const float* src = xw0 + (size_t)row * 1216 + (off < 0 ? 0 : off);
            float4 v = *(const float4*)src;
            if (off < 0) v.w = 0.f;                 // x[-1] pad (q=0 only)
            const uint ux = __float_as_uint(v.x), uy = __float_as_uint(v.y);
            const uint uz = __float_as_uint(v.z), uw = __float_as_uint(v.w);
            ushort4 hs = make_ushort4((ushort)(ux >> 16), (ushort)(uy >> 16),
                                      (ushort)(uz >> 16), (ushort)(uw >> 16));
            const float lx = v.x - __uint_as_float(ux & 0xFFFF0000u);
            const float ly = v.y - __uint_as_float(uy & 0xFFFF0000u);
            const float lz = v.z - __uint_as_float(uz & 0xFFFF0000u);
            const float lw = v.w - __uint_as_float(uw & 0xFFFF0000u);
            ushort4 ls = make_ushort4((ushort)(__float_as_uint(lx) >> 16),
                                      (ushort)(__float_as_uint(ly) >> 16),
                                      (ushort)(__float_as_uint(lz) >> 16),
                                      (ushort)(__float_as_uint(lw) >> 16));
            *(ushort4*)&hp[row * XPS + 4 * c4] = hs;
            *(ushort4*)&lp[row * XPS + 4 * c4] = ls;
        }

        // ---- conv1 MFMA + relu+pool5 -> h1t[series][tw][ch] ----
        // B[k]=plane[s][base+(k mod 16)]; A: w_hi@3..12, w_lo@19..28 ->
        // two MFMAs (B=x_hi, B=x_lo) = exact fp32 w*x.
        #pragma unroll
        for (int tw = 0; tw < 3; ++tw) {
            f32x4 mx0 = (f32x4){0.f,0.f,0.f,0.f};   // relu folded into pool
            f32x4 mx1 = (f32x4){0.f,0.f,0.f,0.f};
            #pragma unroll
            for (int ts = 0; ts < 5; ++ts) {
                const int tl = 5 * tw + ts;         // 0..14
                const int jb = 8 * tl + 8 * qm;
                bf16x8 bh = *(const bf16x8*)(hp + lm * XPS + jb);
                bf16x8 bl = *(const bf16x8*)(lp + lm * XPS + jb);
                f32x4 a0 = __builtin_amdgcn_mfma_f32_16x16x32_bf16(wA0, bh, b1i0, 0, 0, 0);
                a0 = __builtin_amdgcn_mfma_f32_16x16x32_bf16(wA0, bl, a0, 0, 0, 0);
                f32x4 a1 = __builtin_amdgcn_mfma_f32_16x16x32_bf16(wA1, bh, b1i1, 0, 0, 0);
                a1 = __builtin_amdgcn_mfma_f32_16x16x32_bf16(wA1, bl, a1, 0, 0, 0);
                #pragma unroll
                for (int r = 0; r < 4; ++r) {
                    mx0[r] = fmaxf(mx0[r], a0[r]);
                    mx1[r] = fmaxf(mx1[r], a1[r]);
                }
            }
            // D: col=lm (series), row=quad*4+r (ch) -> h1t[lm][tw][ch]
            ushort4 p0, p1;
            p0.x = f2bf(mx0[0]); p0.y = f2bf(mx0[1]);
            p0.z = f2bf(mx0[2]); p0.w = f2bf(mx0[3]);
            p1.x = f2bf(mx1[0]); p1.y = f2bf(mx1[1]);
            p1.z = f2bf(mx1[2]); p1.w = f2bf(mx1[3]);
            *(ushort4*)&h1t[lm * H1S + 32 * tw + quad * 4]      = p0;  // ch 0-15
            *(ushort4*)&h1t[lm * H1S + 32 * tw + 16 + quad * 4] = p1;  // ch 16-31
        }

        // ---- conv2: 12 MFMA vs w2bL (A-frag from h1t, exact R0 layout) ----
        f32x4 acc[4];
        #pragma unroll
        for (int nt = 0; nt < 4; ++nt) acc[nt] = (f32x4){0.f,0.f,0.f,0.f};
        #pragma unroll
        for (int kc = 0; kc < 3; ++kc) {
            bf16x8 afv = *(const bf16x8*)&h1t[lm * H1S + 32 * kc + quad * 8];
            #pragma unroll
            for (int nt = 0; nt < 4; ++nt) {
                bf16x8 bfr = *(const bf16x8*)(w2bL + (nt*16 + lm)*W2S + kc*32 + quad*8);
                acc[nt] = __builtin_amdgcn_mfma_f32_16x16x32_bf16(afv, bfr, acc[nt], 0, 0, 0);
            }
        }

        // pool2 windows over q: {0,1},{2,3,4},{5,6,7},{8,9}  (wave-uniform)
        const bool fresh = (q == 0 || q == 2 || q == 5 || q == 8);
        #pragma unroll
        for (int nt = 0; nt < 4; ++nt)
            #pragma unroll
            for (int r = 0; r < 4; ++r)
                cur[nt][r] = fresh ? acc[nt][r] : fmaxf(cur[nt][r], acc[nt][r]);

        if (q == 1 || q == 4 || q == 7 || q == 9) {     // window close
            const int w = (q == 1) ? 0 : (q == 4) ? 1 : (q == 7) ? 2 : 3;
            #pragma unroll
            for (int nt = 0; nt < 4; ++nt)
                #pragma unroll
                for (int r = 0; r < 4; ++r) {
                    float f = fmaxf(cur[nt][r] + bias2[nt], 0.f);
                    uint hb = (uint)f2bf(f);
                    if (w == 0)      pk[nt][r].x  = hb;
                    else if (w == 1) pk[nt][r].x |= hb << 16;
                    else if (w == 2) pk[nt][r].y  = hb;
                    else             pk[nt][r].y |= hb << 16;
                }
        }
    }

    // ---- sh2 tile (overlays dead planes): rows = series, k = c2*4 + w ----
    ushort* shw = arena[wave];
    #pragma unroll
    for (int nt = 0; nt < 4; ++nt)
        #pragma unroll
        for (int r = 0; r < 4; ++r)
            *(uint2*)(shw + (quad*4 + r) * S2 + (nt*16 + lm) * 4) = pk[nt][r];

    // ---- conv3 GEMM (16 series x 128 cols, K=256) + logits partials ----
    // B-operand: raw w3 f32 + inline f2bf (bit-identical to old k0_prep)
    bf16x8 afr[8];
    #pragma unroll
    for (int kc = 0; kc < 8; ++kc)          // A-frag: row lm, 16B contiguous
        afr[kc] = *(const bf16x8*)(shw + lm * S2 + kc * 32 + quad * 8);

    const int node0 = bn0 & 127;
    const float* wlr = wl + (node0 + quad * 4) * 128 + lm;
    float a0 = 0.f, a1 = 0.f, a2 = 0.f;
    for (int nt3 = 0; nt3 < 8; ++nt3) {     // dynamic: small icache
        f32x4 acc3 = (f32x4){0.f, 0.f, 0.f, 0.f};
        const float* w3r = w3 + (size_t)(nt3 * 16 + lm) * 256 + quad * 8;
        #pragma unroll
        for (int kc = 0; kc < 8; ++kc) {
            float4 u0 = *(const float4*)(w3r + kc * 32);
            float4 u1 = *(const float4*)(w3r + kc * 32 + 4);
            union { ushort u[8]; bf16x8 v; } bf;
            bf.u[0] = f2bf(u0.x); bf.u[1] = f2bf(u0.y);
            bf.u[2] = f2bf(u0.z); bf.u[3] = f2bf(u0.w);
            bf.u[4] = f2bf(u1.x); bf.u[5] = f2bf(u1.y);
            bf.u[6] = f2bf(u1.z); bf.u[7] = f2bf(u1.w);
            acc3 = __builtin_amdgcn_mfma_f32_16x16x32_bf16(afr[kc], bf.v, acc3, 0, 0, 0);
        }
        const float b3v = b3[nt3 * 16 + lm];
        #pragma unroll
        for (int r = 0; r < 4; ++r) {       // feat value, never materialized
            float f = fmaxf(acc3[r] + b3v, 0.f);
            const float* wp = wlr + r * 128 + nt3 * 16;
            a0 = fmaf(f, wp[0],     a0);
            a1 = fmaf(f, wp[16384], a1);
            a2 = fmaf(f, wp[32768], a2);
        }
    }

    #pragma unroll
    for (int off = 32; off > 0; off >>= 1) {
        a0 += __shfl_xor(a0, off);
        a1 += __shfl_xor(a1, off);
        a2 += __shfl_xor(a2, off);
    }
    if (lane == 0) { red[wave][0] = a0; red[wave][1] = a1; red[wave][2] = a2; }
    __syncthreads();

    // ---- publish partials (device-scope release) + elect last block ----
    if (tid < 3) {
        float s = red[0][tid] + red[1][tid] + red[2][tid] + red[3][tid];
        __hip_atomic_store(&partials[blockIdx.x * 3 + tid], s,
                           __ATOMIC_RELEASE, __HIP_MEMORY_SCOPE_AGENT);
    }
    __syncthreads();
    if (tid == 0) {
        uint old = __hip_atomic_fetch_add(cnt, 1u, __ATOMIC_ACQ_REL,
                                          __HIP_MEMORY_SCOPE_AGENT);
        sh_last = (old == 511u);
    }
    __syncthreads();

    if (sh_last) {                          // last block: reduce + softmax
        const int b = tid;                  // 256 batches
        float l0 = blg[0], l1 = blg[1], l2 = blg[2];
        #pragma unroll
        for (int j = 0; j < 2; ++j) {
            const float* pr = partials + (2 * b + j) * 3;
            l0 += __hip_atomic_load(pr + 0, __ATOMIC_ACQUIRE, __HIP_MEMORY_SCOPE_AGENT);
            l1 += __hip_atomic_load(pr + 1, __ATOMIC_ACQUIRE, __HIP_MEMORY_SCOPE_AGENT);
            l2 += __hip_atomic_load(pr + 2, __ATOMIC_ACQUIRE, __HIP_MEMORY_SCOPE_AGENT);
        }
        float m  = fmaxf(l0, fmaxf(l1, l2));
        float e0 = expf(l0 - m), e1 = expf(l1 - m), e2 = expf(l2 - m);
        float s  = e0 + e1 + e2;
        out[b*3+0] = e0 / s; out[b*3+1] = e1 / s; out[b*3+2] = e2 / s;
    }
}

extern "C" void kernel_launch(void* const* d_in, const int* in_sizes, int n_in,
                              void* d_out, int out_size, void* d_ws, size_t ws_size,
                              hipStream_t stream) {
    const float* x  = (const float*)d_in[0];
    const float* w1 = (const float*)d_in[1];
    const float* b1 = (const float*)d_in[2];
    const float* w2 = (const float*)d_in[3];
    const float* b2 = (const float*)d_in[4];
    const float* w3 = (const float*)d_in[5];
    const float* b3 = (const float*)d_in[6];
    const float* wl = (const float*)d_in[7];
    const float* bl = (const float*)d_in[8];
    float* out = (float*)d_out;

    // ws: partials[512][3] at 0 | counter at 8192
    float* partials = (float*)d_ws;
    uint*  cnt      = (uint*)((char*)d_ws + 8192);

    hipMemsetAsync(cnt, 0, 4, stream);      // graph-capturable stream op
    k_fused<<<512, 256, 0, stream>>>(x, w1, b1, w2, b2, w3, b3, wl, bl,
                                     partials, cnt, out);
}

// Round 10
// 261.329 us; speedup vs baseline: 1.0816x; 1.0816x over previous
//
#include <hip/hip_runtime.h>
#include <math.h>

// Fully-fused pipeline, 3 kernels (R7 structure restored; R9 merge reverted).
// R10: CLEAN TLP TEST -- q-split wave pairs on the R7 MFMA-conv1 structure.
// Block = 128 thr = 2 waves sharing one 16-series tile: wave h owns
// q in [5h,5h+5) (pool2 windows {0,1} vs {2,3} are q-disjoint), running
// R7's exact per-q pipeline (coalesced stage -> hi/lo planes -> conv1 = 60
// MFMA + pool1 -> h1t -> conv2 = 12 MFMA -> pool2) in its own wave-private
// LDS arena, ZERO barriers in the q loop. The halves meet at two barriers:
// disjoint-4B-word writes into the shared sh2 tile (overlaid on wave 0's
// dead arena), then conv3 (K=256) split by output channel (nt3 = 4h..4h+3).
// Per-wave serial chain HALVES (5 q's) and waves double (4096 total, LDS
// 24.1KB -> 6 blocks/CU -> 3 waves/SIMD resident vs 2 before).
// R1/R5's TLP nulls were confounded (barrier coupling / divergent loads);
// this keeps the R7 load pattern bit-identical. absmax must stay 0.00390625.
//   k0    : w2 -> w2b bf16 [64][96]; w3 -> w3b; w1 -> w1b [2][16][32] hi/lo
//   k_fused (2048 blocks x 128): per ql: stage -> conv1 MFMA (hi/lo split,
//     exact fp32) -> h1t -> conv2 MFMA -> pool2 -> pk -> barrier -> sh2 ->
//     barrier -> conv3 GEMM -> relu -> logits partials -> butterfly ->
//     partials[2048][3]
//   k_soft: 1 block: logits = sum of 8 partials + bl, softmax -> out.

typedef __attribute__((ext_vector_type(8))) short bf16x8;
typedef __attribute__((ext_vector_type(4))) float f32x4;

__device__ __forceinline__ ushort f2bf(float f) {
    union { float f; uint u; } c; c.f = f;
    return (ushort)((c.u + 0x7FFFu + ((c.u >> 16) & 1u)) >> 16);   // RNE
}

#define S2  264   // sh2 row stride (ushorts): 528B rows, 16B-aligned
#define XPS 136   // x hi/lo plane row stride (ushorts): 272B, 16B-aligned
#define H1S 104   // h1t row stride (ushorts): 208B; 52 dw -> 2-way-free banks

__global__ void k0_prep(const float* __restrict__ w2, ushort* __restrict__ w2b,
                        const float* __restrict__ w3, ushort* __restrict__ w3b,
                        const float* __restrict__ w1, ushort* __restrict__ w1b) {
    int i = blockIdx.x * 256 + threadIdx.x;
    if (i < 6144) {                     // w2[c][ci][d] -> w2b[c][d*32+ci]
        int c = i / 96, r = i - c * 96;
        int ci = r / 3, d = r - ci * 3;
        w2b[c * 96 + d * 32 + ci] = f2bf(w2[i]);
    }
    int j = i - 6144;
    if (j >= 0 && j < 32768) w3b[j] = f2bf(w3[j]);
    int j3 = i - 38912;                 // w1b[H][16 ch][32 k]: hi@3..12, lo@19..28
    if (j3 >= 0 && j3 < 1024) {
        int H = j3 >> 9, r9 = j3 & 511, c = r9 >> 5, k = r9 & 31;
        int ch = H * 16 + c;
        ushort val = 0;
        if (k >= 3 && k <= 12) {
            val = (ushort)(__float_as_uint(w1[ch * 10 + k - 3]) >> 16);  // hi=trunc
        } else if (k >= 19 && k <= 28) {
            float w = w1[ch * 10 + k - 19];
            float hf = __uint_as_float(__float_as_uint(w) & 0xFFFF0000u);
            val = f2bf(w - hf);                                          // lo=RNE
        }
        w1b[j3] = val;
    }
}

__global__ __launch_bounds__(128) void k_fused(
    const float* __restrict__ x,     // [32768][1216]
    const float* __restrict__ b1,    // [32]
    const ushort* __restrict__ w2b,  // [64][96] ; w1b at w2b+6144
    const float* __restrict__ b2,    // [64]
    const ushort* __restrict__ w3b,  // [128][256]
    const float* __restrict__ b3,    // [128]
    const float* __restrict__ wl,    // [3][16384]
    float* __restrict__ partials)    // [2048][3]
{
    // per-wave arena: hi plane [16][XPS] | lo plane [16][XPS] | h1t [16][H1S]
    // = 6016 ushorts (12,032 B) x 2 waves. The shared sh2 tile (4224 ushorts)
    // overlays arena[0] after both q-loops finish (barrier-protected).
    __shared__ __align__(16) ushort arena[2][6016];   // 24,064 B
    __shared__ float red[2][3];
    const int tid  = threadIdx.x;
    const int h    = tid >> 6, lane = tid & 63;       // h = q-half owner
    const int lm   = lane & 15, quad = lane >> 4, qm = quad & 1;
    const int bn0  = blockIdx.x * 16;                 // block's 16 series
    const float* xw0 = x + (size_t)bn0 * 1216;

    ushort* hp  = arena[h];               // x_hi plane
    ushort* lp  = hp + 16 * XPS;          // x_lo plane
    ushort* h1t = lp + 16 * XPS;          // per-q pooled conv1 tile [16][3][32]

    // hoisted fragments / biases
    const ushort* w1b = w2b + 6144;
    const bf16x8 wA0 = *(const bf16x8*)(w1b + lm * 32 + quad * 8);        // ch 0-15
    const bf16x8 wA1 = *(const bf16x8*)(w1b + 512 + lm * 32 + quad * 8);  // ch 16-31
    const f32x4  b1i0 = *(const f32x4*)(b1 + quad * 4);       // rows quad*4+r
    const f32x4  b1i1 = *(const f32x4*)(b1 + 16 + quad * 4);
    float bias2[4];
    #pragma unroll
    for (int nt = 0; nt < 4; ++nt) bias2[nt] = b2[nt * 16 + lm];

    f32x4 cur[4];
    #pragma unroll
    for (int nt = 0; nt < 4; ++nt) cur[nt] = (f32x4){-3e38f,-3e38f,-3e38f,-3e38f};
    uint pk[4][4];                        // this half's 2 packed windows [nt][r]

    for (int ql = 0; ql < 5; ++ql) {
        const int q = 5 * h + ql;         // this wave's conv2 position
        // ---- stage x[16 rows][fq .. fq+123] -> hi/lo bf16 planes ----
        // (wave-private: no barriers; 32 consecutive lanes cover one row)
        const int fq = 120 * q - 4;
        #pragma unroll
        for (int j = 0; j < 8; ++j) {
            const int idx = lane + 64 * j;          // 0..511
            const int row = idx >> 5, c4 = idx & 31;
            const int off = fq + 4 * c4;
            const float* src = xw0 + (size_t)row * 1216 + (off < 0 ? 0 : off);
            float4 v = *(const float4*)src;
            if (off < 0) v.w = 0.f;                 // x[-1] pad (q=0 only)
            const uint ux = __float_as_uint(v.x), uy = __float_as_uint(v.y);
            const uint uz = __float_as_uint(v.z), uw = __float_as_uint(v.w);
            ushort4 hs = make_ushort4((ushort)(ux >> 16), (ushort)(uy >> 16),
                                      (ushort)(uz >> 16), (ushort)(uw >> 16));
            const float lx = v.x - __uint_as_float(ux & 0xFFFF0000u);
            const float ly = v.y - __uint_as_float(uy & 0xFFFF0000u);
            const float lz = v.z - __uint_as_float(uz & 0xFFFF0000u);
            const float lw = v.w - __uint_as_float(uw & 0xFFFF0000u);
            ushort4 ls = make_ushort4((ushort)(__float_as_uint(lx) >> 16),
                                      (ushort)(__float_as_uint(ly) >> 16),
                                      (ushort)(__float_as_uint(lz) >> 16),
                                      (ushort)(__float_as_uint(lw) >> 16));
            *(ushort4*)&hp[row * XPS + 4 * c4] = hs;
            *(ushort4*)&lp[row * XPS + 4 * c4] = ls;
        }

        // ---- conv1 MFMA + relu+pool5 -> h1t[series][tw][ch] ----
        // B[k]=plane[s][base+(k mod 16)]; A: w_hi@3..12, w_lo@19..28 ->
        // two MFMAs (B=x_hi, B=x_lo) = exact fp32 w*x.
        #pragma unroll
        for (int tw = 0; tw < 3; ++tw) {
            f32x4 mx0 = (f32x4){0.f,0.f,0.f,0.f};   // relu folded into pool
            f32x4 mx1 = (f32x4){0.f,0.f,0.f,0.f};
            #pragma unroll
            for (int ts = 0; ts < 5; ++ts) {
                const int tl = 5 * tw + ts;         // 0..14
                const int jb = 8 * tl + 8 * qm;
                bf16x8 bh = *(const bf16x8*)(hp + lm * XPS + jb);
                bf16x8 bl = *(const bf16x8*)(lp + lm * XPS + jb);
                f32x4 a0 = __builtin_amdgcn_mfma_f32_16x16x32_bf16(wA0, bh, b1i0, 0, 0, 0);
                a0 = __builtin_amdgcn_mfma_f32_16x16x32_bf16(wA0, bl, a0, 0, 0, 0);
                f32x4 a1 = __builtin_amdgcn_mfma_f32_16x16x32_bf16(wA1, bh, b1i1, 0, 0, 0);
                a1 = __builtin_amdgcn_mfma_f32_16x16x32_bf16(wA1, bl, a1, 0, 0, 0);
                #pragma unroll
                for (int r = 0; r < 4; ++r) {
                    mx0[r] = fmaxf(mx0[r], a0[r]);
                    mx1[r] = fmaxf(mx1[r], a1[r]);
                }
            }
            // D: col=lm (series), row=quad*4+r (ch) -> h1t[lm][tw][ch]
            ushort4 p0, p1;
            p0.x = f2bf(mx0[0]); p0.y = f2bf(mx0[1]);
            p0.z = f2bf(mx0[2]); p0.w = f2bf(mx0[3]);
            p1.x = f2bf(mx1[0]); p1.y = f2bf(mx1[1]);
            p1.z = f2bf(mx1[2]); p1.w = f2bf(mx1[3]);
            *(ushort4*)&h1t[lm * H1S + 32 * tw + quad * 4]      = p0;  // ch 0-15
            *(ushort4*)&h1t[lm * H1S + 32 * tw + 16 + quad * 4] = p1;  // ch 16-31
        }

        // ---- conv2: 12 MFMA vs w2b (A-frag from h1t, exact R0 layout) ----
        f32x4 acc[4];
        #pragma unroll
        for (int nt = 0; nt < 4; ++nt) acc[nt] = (f32x4){0.f,0.f,0.f,0.f};
        #pragma unroll
        for (int kc = 0; kc < 3; ++kc) {
            bf16x8 afv = *(const bf16x8*)&h1t[lm * H1S + 32 * kc + quad * 8];
            #pragma unroll
            for (int nt = 0; nt < 4; ++nt) {
                bf16x8 bfr = *(const bf16x8*)(w2b + (nt*16 + lm)*96 + kc*32 + quad*8);
                acc[nt] = __builtin_amdgcn_mfma_f32_16x16x32_bf16(afv, bfr, acc[nt], 0, 0, 0);
            }
        }

        // pool2 bookkeeping for this half (wave-uniform):
        // h0: windows {0,1},{2,3,4}; h1: {5,6,7},{8,9}
        // h0: fresh ql 0,2; close ql 1 (slot0), 4 (slot1)
        // h1: fresh ql 0,3; close ql 2 (slot0), 4 (slot1)
        const bool fresh = (ql == 0) || (ql == 2 + h);
        #pragma unroll
        for (int nt = 0; nt < 4; ++nt)
            #pragma unroll
            for (int r = 0; r < 4; ++r)
                cur[nt][r] = fresh ? acc[nt][r] : fmaxf(cur[nt][r], acc[nt][r]);

        if (ql == 1 + h || ql == 4) {           // window close
            const int w = (ql == 4) ? 1 : 0;    // slot within this half's uint
            #pragma unroll
            for (int nt = 0; nt < 4; ++nt)
                #pragma unroll
                for (int r = 0; r < 4; ++r) {
                    float f = fmaxf(cur[nt][r] + bias2[nt], 0.f);
                    uint hb = (uint)f2bf(f);
                    if (w == 0) pk[nt][r]  = hb;
                    else        pk[nt][r] |= hb << 16;
                }
        }
    }

    // ---- shared sh2 tile (overlays arena[0], both waves' arenas dead) ----
    __syncthreads();                      // both q-loops done before overlay
    ushort* sh2 = arena[0];               // [16][S2]
    #pragma unroll
    for (int nt = 0; nt < 4; ++nt)
        #pragma unroll
        for (int r = 0; r < 4; ++r)       // k = c2*4 + w; half h owns w=2h,2h+1
            *(uint*)(sh2 + (quad*4 + r) * S2 + (nt*16 + lm) * 4 + 2 * h) = pk[nt][r];
    __syncthreads();

    // ---- conv3 GEMM (16 series x 64 cols per wave, K=256) + logits ----
    bf16x8 afr[8];
    #pragma unroll
    for (int kc = 0; kc < 8; ++kc)        // A-frag: row lm, 16B contiguous
        afr[kc] = *(const bf16x8*)(sh2 + lm * S2 + kc * 32 + quad * 8);

    const int node0 = bn0 & 127;
    const float* wlr = wl + (node0 + quad * 4) * 128 + lm;
    float a0 = 0.f, a1 = 0.f, a2 = 0.f;
    #pragma unroll
    for (int t3 = 0; t3 < 4; ++t3) {      // this wave's channel quarter-pair
        const int nt3 = 4 * h + t3;
        f32x4 acc3 = (f32x4){0.f, 0.f, 0.f, 0.f};
        const ushort* bb = w3b + (size_t)(nt3 * 16 + lm) * 256 + quad * 8;
        #pragma unroll
        for (int kc = 0; kc < 8; ++kc) {
            bf16x8 bf3 = *(const bf16x8*)(bb + kc * 32);
            acc3 = __builtin_amdgcn_mfma_f32_16x16x32_bf16(afr[kc], bf3, acc3, 0, 0, 0);
        }
        const float b3v = b3[nt3 * 16 + lm];
        #pragma unroll
        for (int r = 0; r < 4; ++r) {     // feat value, never materialized
            float f = fmaxf(acc3[r] + b3v, 0.f);
            const float* wp = wlr + r * 128 + nt3 * 16;
            a0 = fmaf(f, wp[0],     a0);
            a1 = fmaf(f, wp[16384], a1);
            a2 = fmaf(f, wp[32768], a2);
        }
    }

    #pragma unroll
    for (int off = 32; off > 0; off >>= 1) {
        a0 += __shfl_xor(a0, off);
        a1 += __shfl_xor(a1, off);
        a2 += __shfl_xor(a2, off);
    }
    if (lane == 0) { red[h][0] = a0; red[h][1] = a1; red[h][2] = a2; }
    __syncthreads();
    if (tid < 3) {
        partials[blockIdx.x * 3 + tid] = red[0][tid] + red[1][tid];
    }
}

// logits = sum of 8 partials rows + bl -> softmax
__global__ void k_soft(const float* __restrict__ partials,
                       const float* __restrict__ bl,
                       float* __restrict__ out) {
    const int b = threadIdx.x;      // 256 batches, 1 block
    float l0 = bl[0], l1 = bl[1], l2 = bl[2];
    #pragma unroll
    for (int j = 0; j < 8; ++j) {
        const float* pr = partials + (8*b + j) * 3;
        l0 += pr[0]; l1 += pr[1]; l2 += pr[2];
    }
    float m  = fmaxf(l0, fmaxf(l1, l2));
    float e0 = expf(l0 - m), e1 = expf(l1 - m), e2 = expf(l2 - m);
    float s  = e0 + e1 + e2;
    out[b*3+0] = e0 / s; out[b*3+1] = e1 / s; out[b*3+2] = e2 / s;
}

extern "C" void kernel_launch(void* const* d_in, const int* in_sizes, int n_in,
                              void* d_out, int out_size, void* d_ws, size_t ws_size,
                              hipStream_t stream) {
    const float* x  = (const float*)d_in[0];
    const float* w1 = (const float*)d_in[1];
    const float* b1 = (const float*)d_in[2];
    const float* w2 = (const float*)d_in[3];
    const float* b2 = (const float*)d_in[4];
    const float* w3 = (const float*)d_in[5];
    const float* b3 = (const float*)d_in[6];
    const float* wl = (const float*)d_in[7];
    const float* bl = (const float*)d_in[8];
    float* out = (float*)d_out;

    // ws: [w2b 12KB | w1b 2KB (first 16KB slot)] | w3b 64KB | partials 24KB
    ushort* w2b      = (ushort*)d_ws;
    ushort* w1b      = w2b + 6144;
    ushort* w3b      = (ushort*)((char*)d_ws + 16384);
    float*  partials = (float*)((char*)d_ws + 16384 + 65536);

    k0_prep<<<156, 256, 0, stream>>>(w2, w2b, w3, w3b, w1, w1b);
    k_fused<<<2048, 128, 0, stream>>>(x, b1, w2b, b2, w3b, b3, wl, partials);
    k_soft<<<1, 256, 0, stream>>>(partials, bl, out);
}

// Round 11
// 257.116 us; speedup vs baseline: 1.0993x; 1.0164x over previous
//
#include <hip/hip_runtime.h>
#include <math.h>

// Fully-fused pipeline, one heavyweight kernel + prep + softmax.
// R11 = R7 base (best: 257.3) with SINGLE x-plane conv1. Session evidence:
// only stream-size cuts win (R7 -33%); latency/occupancy/coalescing all null
// (R1,R2,R5,R6,R8,R10) -> per-SIMD pipe time scales with instructions.
// Biggest stream block was hi/lo x staging (~216 VALU/q = 40% of VALU) +
// its 2nd LDS plane + 2nd conv1 MFMA set. x drops to single RNE-bf16 plane;
// w KEEPS its exact hi/lo split (free, in A's spare K-slots: slots 3..12 =
// w_hi, 19..28 = w_lo, B slot k reads plane[(k mod 16)] so one MFMA gives
// sum (w_hi+w_lo)*x_hi = w*x_hi exactly). Added error ~1e-4 (~1/3 of the
// existing h1 bf16 rounding) -> absmax ~unchanged.
// Cuts per q: convert 27->14 VALU/j, plane writes 16->8, conv1 MFMA 60->30,
// conv1 LDS reads 30->15.
//   k0    : w2 -> w2b bf16 [64][96]; w3 -> w3b; w1 -> w1b [2][16][32] hi/lo
//   k_fused: per q: stage 16x128 floats -> RNE bf16 plane -> conv1 = 30 MFMA
//     (15 t x 2 chhalf) + pool1 -> h1t [16][3][32] -> conv2 = 12 MFMA vs w2b
//     -> bias+relu+pool2 -> pk regs -> (after loop) sh2 tile -> conv3 GEMM
//     (K=256) vs w3b -> relu -> logits partials -> wave butterfly ->
//     per-block partial[512][3]
//   k_soft: 1 block: logits = partials[2b]+partials[2b+1]+bl, softmax.

typedef __attribute__((ext_vector_type(8))) short bf16x8;
typedef __attribute__((ext_vector_type(4))) float f32x4;

__device__ __forceinline__ ushort f2bf(float f) {
    union { float f; uint u; } c; c.f = f;
    return (ushort)((c.u + 0x7FFFu + ((c.u >> 16) & 1u)) >> 16);   // RNE
}

#define S2  264   // sh2 row stride (ushorts): 528B rows, 16B-aligned
#define XPS 136   // x plane row stride (ushorts): 272B; 68 dw % 32 = 4 -> spread
#define H1S 104   // h1t row stride (ushorts): 208B; 52 dw -> 2-way-free banks
#define ARW 4224  // per-wave arena ushorts: max(plane+h1t = 3840, sh2 = 4224)

__global__ void k0_prep(const float* __restrict__ w2, ushort* __restrict__ w2b,
                        const float* __restrict__ w3, ushort* __restrict__ w3b,
                        const float* __restrict__ w1, ushort* __restrict__ w1b) {
    int i = blockIdx.x * 256 + threadIdx.x;
    if (i < 6144) {                     // w2[c][ci][d] -> w2b[c][d*32+ci]
        int c = i / 96, r = i - c * 96;
        int ci = r / 3, d = r - ci * 3;
        w2b[c * 96 + d * 32 + ci] = f2bf(w2[i]);
    }
    int j = i - 6144;
    if (j >= 0 && j < 32768) w3b[j] = f2bf(w3[j]);
    int j3 = i - 38912;                 // w1b[H][16 ch][32 k]: hi@3..12, lo@19..28
    if (j3 >= 0 && j3 < 1024) {
        int H = j3 >> 9, r9 = j3 & 511, c = r9 >> 5, k = r9 & 31;
        int ch = H * 16 + c;
        ushort val = 0;
        if (k >= 3 && k <= 12) {
            val = (ushort)(__float_as_uint(w1[ch * 10 + k - 3]) >> 16);  // hi=trunc
        } else if (k >= 19 && k <= 28) {
            float w = w1[ch * 10 + k - 19];
            float hf = __uint_as_float(__float_as_uint(w) & 0xFFFF0000u);
            val = f2bf(w - hf);                                          // lo=RNE
        }
        w1b[j3] = val;
    }
}

__global__ __launch_bounds__(256) void k_fused(
    const float* __restrict__ x,     // [32768][1216]
    const float* __restrict__ b1,    // [32]
    const ushort* __restrict__ w2b,  // [64][96] ; w1b at w2b+6144
    const float* __restrict__ b2,    // [64]
    const ushort* __restrict__ w3b,  // [128][256]
    const float* __restrict__ b3,    // [128]
    const float* __restrict__ wl,    // [3][16384]
    float* __restrict__ partials)    // [512][3]
{
    // per-wave arena: x plane [16][XPS] (2176) | h1t [16][H1S] (1664);
    // the sh2 tile (4224) overlays the whole arena after the q loop
    // (wave-private: same wave writes then reads, no barrier needed).
    __shared__ __align__(16) ushort arena[4][ARW];    // 33,792 B
    __shared__ float red[4][3];
    const int wave = threadIdx.x >> 6, lane = threadIdx.x & 63;
    const int lm   = lane & 15, quad = lane >> 4, qm = quad & 1;
    const int bn0  = blockIdx.x * 64 + wave * 16;
    const float* xw0 = x + (size_t)bn0 * 1216;     // wave's 16 series rows

    ushort* hp  = arena[wave];            // x bf16 plane (RNE)
    ushort* h1t = hp + 16 * XPS;          // per-q pooled conv1 tile [16][3][32]

    // hoisted fragments / biases
    const ushort* w1b = w2b + 6144;
    const bf16x8 wA0 = *(const bf16x8*)(w1b + lm * 32 + quad * 8);        // ch 0-15
    const bf16x8 wA1 = *(const bf16x8*)(w1b + 512 + lm * 32 + quad * 8);  // ch 16-31
    const f32x4  b1i0 = *(const f32x4*)(b1 + quad * 4);       // rows quad*4+r
    const f32x4  b1i1 = *(const f32x4*)(b1 + 16 + quad * 4);
    float bias2[4];
    #pragma unroll
    for (int nt = 0; nt < 4; ++nt) bias2[nt] = b2[nt * 16 + lm];

    f32x4 cur[4];
    #pragma unroll
    for (int nt = 0; nt < 4; ++nt) cur[nt] = (f32x4){-3e38f,-3e38f,-3e38f,-3e38f};
    uint2 pk[4][4];                       // packed pooled conv2 bf16 [nt][r]

    for (int q = 0; q < 10; ++q) {
        // ---- stage x[16 rows][fq .. fq+123] -> RNE bf16 plane ----
        // (wave-private: no barriers; 32 consecutive lanes cover one row)
        const int fq = 120 * q - 4;
        #pragma unroll
        for (int j = 0; j < 8; ++j) {
            const int idx = lane + 64 * j;          // 0..511
            const int row = idx >> 5, c4 = idx & 31;
            const int off = fq + 4 * c4;
            const float* src = xw0 + (size_t)row * 1216 + (off < 0 ? 0 : off);
            float4 v = *(const float4*)src;
            if (off < 0) v.w = 0.f;                 // x[-1] pad (q=0 only)
            ushort4 hs = make_ushort4(f2bf(v.x), f2bf(v.y), f2bf(v.z), f2bf(v.w));
            *(ushort4*)&hp[row * XPS + 4 * c4] = hs;
        }

        // ---- conv1 MFMA + relu+pool5 -> h1t[series][tw][ch] ----
        // B[k][s] = plane[s][jb + (k mod 16)]; A slots 3..12 = w_hi,
        // 19..28 = w_lo -> ONE MFMA = sum (w_hi+w_lo)*x = exact-w dot.
        #pragma unroll
        for (int tw = 0; tw < 3; ++tw) {
            f32x4 mx0 = (f32x4){0.f,0.f,0.f,0.f};   // relu folded into pool
            f32x4 mx1 = (f32x4){0.f,0.f,0.f,0.f};
            #pragma unroll
            for (int ts = 0; ts < 5; ++ts) {
                const int tl = 5 * tw + ts;         // 0..14
                const int jb = 8 * tl + 8 * qm;
                bf16x8 bh = *(const bf16x8*)(hp + lm * XPS + jb);
                f32x4 a0 = __builtin_amdgcn_mfma_f32_16x16x32_bf16(wA0, bh, b1i0, 0, 0, 0);
                f32x4 a1 = __builtin_amdgcn_mfma_f32_16x16x32_bf16(wA1, bh, b1i1, 0, 0, 0);
                #pragma unroll
                for (int r = 0; r < 4; ++r) {
                    mx0[r] = fmaxf(mx0[r], a0[r]);
                    mx1[r] = fmaxf(mx1[r], a1[r]);
                }
            }
            // D: col=lm (series), row=quad*4+r (ch) -> h1t[lm][tw][ch]
            ushort4 p0, p1;
            p0.x = f2bf(mx0[0]); p0.y = f2bf(mx0[1]);
            p0.z = f2bf(mx0[2]); p0.w = f2bf(mx0[3]);
            p1.x = f2bf(mx1[0]); p1.y = f2bf(mx1[1]);
            p1.z = f2bf(mx1[2]); p1.w = f2bf(mx1[3]);
            *(ushort4*)&h1t[lm * H1S + 32 * tw + quad * 4]      = p0;  // ch 0-15
            *(ushort4*)&h1t[lm * H1S + 32 * tw + 16 + quad * 4] = p1;  // ch 16-31
        }

        // ---- conv2: 12 MFMA vs w2b (A-frag from h1t, exact R0 layout) ----
        f32x4 acc[4];
        #pragma unroll
        for (int nt = 0; nt < 4; ++nt) acc[nt] = (f32x4){0.f,0.f,0.f,0.f};
        #pragma unroll
        for (int kc = 0; kc < 3; ++kc) {
            bf16x8 afv = *(const bf16x8*)&h1t[lm * H1S + 32 * kc + quad * 8];
            #pragma unroll
            for (int nt = 0; nt < 4; ++nt) {
                bf16x8 bfr = *(const bf16x8*)(w2b + (nt*16 + lm)*96 + kc*32 + quad*8);
                acc[nt] = __builtin_amdgcn_mfma_f32_16x16x32_bf16(afv, bfr, acc[nt], 0, 0, 0);
            }
        }

        // pool2 windows over q: {0,1},{2,3,4},{5,6,7},{8,9}  (wave-uniform)
        const bool fresh = (q == 0 || q == 2 || q == 5 || q == 8);
        #pragma unroll
        for (int nt = 0; nt < 4; ++nt)
            #pragma unroll
            for (int r = 0; r < 4; ++r)
                cur[nt][r] = fresh ? acc[nt][r] : fmaxf(cur[nt][r], acc[nt][r]);

        if (q == 1 || q == 4 || q == 7 || q == 9) {     // window close
            const int w = (q == 1) ? 0 : (q == 4) ? 1 : (q == 7) ? 2 : 3;
            #pragma unroll
            for (int nt = 0; nt < 4; ++nt)
                #pragma unroll
                for (int r = 0; r < 4; ++r) {
                    float f = fmaxf(cur[nt][r] + bias2[nt], 0.f);
                    uint hb = (uint)f2bf(f);
                    if (w == 0)      pk[nt][r].x  = hb;
                    else if (w == 1) pk[nt][r].x |= hb << 16;
                    else if (w == 2) pk[nt][r].y  = hb;
                    else             pk[nt][r].y |= hb << 16;
                }
        }
    }

    // ---- sh2 tile (overlays dead plane+h1t): rows = series, k = c2*4+w ----
    ushort* shw = arena[wave];
    #pragma unroll
    for (int nt = 0; nt < 4; ++nt)
        #pragma unroll
        for (int r = 0; r < 4; ++r)
            *(uint2*)(shw + (quad*4 + r) * S2 + (nt*16 + lm) * 4) = pk[nt][r];

    // ---- conv3 GEMM (16 series x 128 cols, K=256) + logits partials ----
    bf16x8 afr[8];
    #pragma unroll
    for (int kc = 0; kc < 8; ++kc)          // A-frag: row lm, 16B contiguous
        afr[kc] = *(const bf16x8*)(shw + lm * S2 + kc * 32 + quad * 8);

    const int node0 = bn0 & 127;
    const float* wlr = wl + (node0 + quad * 4) * 128 + lm;
    float a0 = 0.f, a1 = 0.f, a2 = 0.f;
    for (int nt3 = 0; nt3 < 8; ++nt3) {     // dynamic: small icache
        f32x4 acc3 = (f32x4){0.f, 0.f, 0.f, 0.f};
        const ushort* bb = w3b + (size_t)(nt3 * 16 + lm) * 256 + quad * 8;
        #pragma unroll
        for (int kc = 0; kc < 8; ++kc) {
            bf16x8 bf3 = *(const bf16x8*)(bb + kc * 32);
            acc3 = __builtin_amdgcn_mfma_f32_16x16x32_bf16(afr[kc], bf3, acc3, 0, 0, 0);
        }
        const float b3v = b3[nt3 * 16 + lm];
        #pragma unroll
        for (int r = 0; r < 4; ++r) {       // feat value, never materialized
            float f = fmaxf(acc3[r] + b3v, 0.f);
            const float* wp = wlr + r * 128 + nt3 * 16;
            a0 = fmaf(f, wp[0],     a0);
            a1 = fmaf(f, wp[16384], a1);
            a2 = fmaf(f, wp[32768], a2);
        }
    }

    #pragma unroll
    for (int off = 32; off > 0; off >>= 1) {
        a0 += __shfl_xor(a0, off);
        a1 += __shfl_xor(a1, off);
        a2 += __shfl_xor(a2, off);
    }
    if (lane == 0) { red[wave][0] = a0; red[wave][1] = a1; red[wave][2] = a2; }
    __syncthreads();
    if (threadIdx.x < 3) {
        float s = red[0][threadIdx.x] + red[1][threadIdx.x]
                + red[2][threadIdx.x] + red[3][threadIdx.x];
        partials[blockIdx.x * 3 + threadIdx.x] = s;
    }
}

// logits = partials[2b] + partials[2b+1] + bl -> softmax
__global__ void k_soft(const float* __restrict__ partials,
                       const float* __restrict__ bl,
                       float* __restrict__ out) {
    const int b = threadIdx.x;      // 256 batches, 1 block
    float l0 = partials[(2*b)*3+0] + partials[(2*b+1)*3+0] + bl[0];
    float l1 = partials[(2*b)*3+1] + partials[(2*b+1)*3+1] + bl[1];
    float l2 = partials[(2*b)*3+2] + partials[(2*b+1)*3+2] + bl[2];
    float m  = fmaxf(l0, fmaxf(l1, l2));
    float e0 = expf(l0 - m), e1 = expf(l1 - m), e2 = expf(l2 - m);
    float s  = e0 + e1 + e2;
    out[b*3+0] = e0 / s; out[b*3+1] = e1 / s; out[b*3+2] = e2 / s;
}

extern "C" void kernel_launch(void* const* d_in, const int* in_sizes, int n_in,
                              void* d_out, int out_size, void* d_ws, size_t ws_size,
                              hipStream_t stream) {
    const float* x  = (const float*)d_in[0];
    const float* w1 = (const float*)d_in[1];
    const float* b1 = (const float*)d_in[2];
    const float* w2 = (const float*)d_in[3];
    const float* b2 = (const float*)d_in[4];
    const float* w3 = (const float*)d_in[5];
    const float* b3 = (const float*)d_in[6];
    const float* wl = (const float*)d_in[7];
    const float* bl = (const float*)d_in[8];
    float* out = (float*)d_out;

    // ws: [w2b 12KB | w1b 2KB (first 16KB slot)] | w3b 64KB | partials 6KB
    ushort* w2b      = (ushort*)d_ws;
    ushort* w1b      = w2b + 6144;
    ushort* w3b      = (ushort*)((char*)d_ws + 16384);
    float*  partials = (float*)((char*)d_ws + 16384 + 65536);

    k0_prep<<<156, 256, 0, stream>>>(w2, w2b, w3, w3b, w1, w1b);
    k_fused<<<512, 256, 0, stream>>>(x, b1, w2b, b2, w3b, b3, wl, partials);
    k_soft<<<1, 256, 0, stream>>>(partials, bl, out);
}